// Round 2
// baseline (124.921 us; speedup 1.0000x reference)
//
#include <hip/hip_runtime.h>
#include <math.h>

// Problem constants: IMG_SIZE=1024, B=64, G=128, A=3, N=1280, stride=8
#define NBOX     1280
#define BVAL     64
#define GVAL     128
#define NFLOAT   (BVAL * GVAL * GVAL * 15)   // 15,728,640 floats = 62.9 MB
#define NVEC     (NFLOAT / 4)                // 3,932,160 float4
#define TILE_V4  960                         // float4 per tile = 3840 floats = 256 groups
#define TILE_F   3840
#define NTILES   (NVEC / TILE_V4)            // 4096 exactly

__device__ __forceinline__ float softplus_f(float z) {
    return fmaxf(z, 0.f) + __logf(1.f + __expf(-fabsf(z)));
}

// blockIdx 0          : target build + dedup (last-write-wins) + gather-adjust
// blockIdx 1..2048    : LDS-staged noobj sweep, 2 tiles each (4096 tiles total)
__global__ void __launch_bounds__(256) yolo_loss_kernel(
    const float* __restrict__ yp,
    const float* __restrict__ gbox,
    const float* __restrict__ anch,
    const int*   __restrict__ bidx,
    float*       __restrict__ out)
{
    __shared__ float sm[TILE_F];   // 15360 B; box block aliases skey/sb over it
    __shared__ float swave[4];

    const int t = threadIdx.x;
    float acc = 0.f;

    if (blockIdx.x == 0) {
        int* skey = (int*)sm;            // [0, NBOX)
        int* sb   = ((int*)sm) + NBOX;   // [NBOX, 2*NBOX)  -> 10 KB total, fits in sm
        // ---- phase 1: per-box scatter key ----
        for (int n = t; n < NBOX; n += 256) {
            float gx = gbox[n * 4 + 0] * 0.125f;
            float gy = gbox[n * 4 + 1] * 0.125f;
            float gw = gbox[n * 4 + 2] * 0.125f;
            float gh = gbox[n * 4 + 3] * 0.125f;
            int gi = (int)gx, gj = (int)gy;
            int best = 0; float bestr = -1.f;
            #pragma unroll
            for (int a = 0; a < 3; a++) {
                float aw = anch[a * 2 + 0] * 0.125f;
                float ah = anch[a * 2 + 1] * 0.125f;
                float inter = fminf(aw, gw) * fminf(ah, gh);
                float uni   = aw * ah + gw * gh - inter;
                float r     = inter / uni;
                if (r > bestr) { bestr = r; best = a; }
            }
            int b = bidx[n];
            skey[n] = ((b * 3 + best) * 128 + gj) * 128 + gi;
            sb[n]   = b;
        }
        __syncthreads();
        // ---- phase 2: dedup scan (batch_idx sorted; last write wins), recompute
        //      target vals for winners, gather pred, accumulate adjustment ----
        for (int n = t; n < NBOX; n += 256) {
            int key = skey[n], b = sb[n];
            bool winner = true;
            for (int m2 = n + 1; m2 < NBOX; m2++) {
                if (sb[m2] != b) break;
                if (skey[m2] == key) { winner = false; break; }
            }
            if (winner) {
                // recompute targets (identical arithmetic to phase 1)
                float gx = gbox[n * 4 + 0] * 0.125f;
                float gy = gbox[n * 4 + 1] * 0.125f;
                float gw = gbox[n * 4 + 2] * 0.125f;
                float gh = gbox[n * 4 + 3] * 0.125f;
                int gi = (int)gx, gj = (int)gy;
                int best = 0; float bestr = -1.f, baw = 1.f, bah = 1.f;
                #pragma unroll
                for (int a = 0; a < 3; a++) {
                    float aw = anch[a * 2 + 0] * 0.125f;
                    float ah = anch[a * 2 + 1] * 0.125f;
                    float inter = fminf(aw, gw) * fminf(ah, gh);
                    float uni   = aw * ah + gw * gh - inter;
                    float r     = inter / uni;
                    if (r > bestr) { bestr = r; best = a; baw = aw; bah = ah; }
                }
                float tx = gx - (float)gi;
                float ty = gy - (float)gj;
                float tw = __logf(gw / baw);
                float th = __logf(gh / bah);
                long base = ((((long)b * GVAL + gj) * GVAL) + gi) * 15 + best * 5;
                float conf = yp[base + 0];
                float px = 1.f / (1.f + __expf(-yp[base + 1]));
                float py = 1.f / (1.f + __expf(-yp[base + 2]));
                float pw = yp[base + 3];
                float ph = yp[base + 4];
                float dx = px - tx, dy = py - ty, dw = pw - tw, dh = ph - th;
                float lp = __logf(1.f + __expf(-fabsf(conf)));
                float sp_pos = fmaxf( conf, 0.f) + lp;   // softplus(conf)
                float sp_neg = fmaxf(-conf, 0.f) + lp;   // softplus(-conf)
                acc += 5.f * (dx * dx + dy * dy + dw * dw + dh * dh)
                     + sp_neg - 0.5f * sp_pos;           // obj minus over-counted noobj
            }
        }
    } else {
        // ---- noobj sweep: 0.5 * sum softplus(conf over channels {0,5,10} mod 15) ----
        const float4* yp4 = (const float4*)yp;
        float4* sm4 = (float4*)sm;
        float lacc = 0.f;
        for (int tile = (int)blockIdx.x - 1; tile < NTILES; tile += (int)gridDim.x - 1) {
            const float4* src = yp4 + (long)tile * TILE_V4;
            // coalesced stage: 960 float4 with 256 threads
            sm4[t]       = src[t];
            sm4[t + 256] = src[t + 256];
            sm4[t + 512] = src[t + 512];
            if (t < 192) sm4[t + 768] = src[t + 768];
            __syncthreads();
            // thread t owns group t: confs at words t*15 + {0,5,10}
            // (stride 15 is coprime to 32 banks; lanes t,t+32 are 2-way = free)
            int w = t * 15;
            lacc += softplus_f(sm[w]) + softplus_f(sm[w + 5]) + softplus_f(sm[w + 10]);
            __syncthreads();   // before LDS reuse next tile
        }
        acc = 0.5f * lacc;
    }

    // ---- block reduction: wave shuffle -> LDS -> one atomic per block ----
    #pragma unroll
    for (int off = 32; off > 0; off >>= 1) acc += __shfl_down(acc, off, 64);
    int lane = t & 63, wid = t >> 6;
    if (lane == 0) swave[wid] = acc;
    __syncthreads();
    if (t == 0) {
        float s = swave[0] + swave[1] + swave[2] + swave[3];
        atomicAdd(out, s);
    }
}

extern "C" void kernel_launch(void* const* d_in, const int* in_sizes, int n_in,
                              void* d_out, int out_size, void* d_ws, size_t ws_size,
                              hipStream_t stream) {
    const float* yp   = (const float*)d_in[0];   // y_pred (B,G,G,15) fp32
    const float* gbox = (const float*)d_in[1];   // ground_bboxes (N,4) fp32
    const float* anch = (const float*)d_in[2];   // anchors (3,2) fp32
    const int*   bidx = (const int*)d_in[3];     // batch_idx (N,) int32

    float* out = (float*)d_out;
    hipMemsetAsync(out, 0, sizeof(float), stream);  // d_out is re-poisoned each replay

    // 1 box block + 2048 sweep blocks (exactly 2 tiles per sweep block)
    yolo_loss_kernel<<<dim3(2049), dim3(256), 0, stream>>>(yp, gbox, anch, bidx, out);
}

// Round 3
// 116.756 us; speedup vs baseline: 1.0699x; 1.0699x over previous
//
#include <hip/hip_runtime.h>
#include <math.h>

// Problem constants: IMG_SIZE=1024, B=64, G=128, A=3, N=1280, stride=8
#define NBOX     1280
#define BVAL     64
#define GVAL     128
#define NFLOAT   (BVAL * GVAL * GVAL * 15)   // 15,728,640 floats = 62.9 MB
#define NVEC     (NFLOAT / 4)                // 3,932,160 float4
#define TILE_V4  960                         // float4 per tile = 3840 floats = 256 groups
#define TILE_F   3840
#define NTILES   (NVEC / TILE_V4)            // 4096 exactly

__device__ __forceinline__ float softplus_f(float z) {
    return fmaxf(z, 0.f) + __logf(1.f + __expf(-fabsf(z)));
}

// blockIdx 0       : target build + dedup (fixed-trip, branch-free) + gather-adjust
// blockIdx 1..2048 : LDS-staged noobj sweep, 2 tiles each (4096 tiles total)
__global__ void __launch_bounds__(256) yolo_loss_kernel(
    const float* __restrict__ yp,
    const float* __restrict__ gbox,
    const float* __restrict__ anch,
    const int*   __restrict__ bidx,
    float*       __restrict__ out)
{
    __shared__ float sm[TILE_F];   // 15360 B; box block aliases skey/scnt over it
    __shared__ float swave[4];

    const int t = threadIdx.x;
    float acc = 0.f;

    if (blockIdx.x == 0) {
        int* skey = (int*)sm;          // [0,1280) keys
        int* scnt = skey + NBOX;       // [0,64) per-batch counts; scnt[0] reused for maxseg

        if (t < BVAL) scnt[t] = 0;
        __syncthreads();

        // ---- phase 1: per-box key (kept in regs too) + batch histogram ----
        int mykey[5];
        #pragma unroll
        for (int k = 0; k < 5; k++) {
            int n = t + k * 256;                     // 5*256 == NBOX exactly
            float gx = gbox[n * 4 + 0] * 0.125f;
            float gy = gbox[n * 4 + 1] * 0.125f;
            float gw = gbox[n * 4 + 2] * 0.125f;
            float gh = gbox[n * 4 + 3] * 0.125f;
            int gi = (int)gx, gj = (int)gy;
            int best = 0; float bestr = -1.f;
            #pragma unroll
            for (int a = 0; a < 3; a++) {
                float aw = anch[a * 2 + 0] * 0.125f;
                float ah = anch[a * 2 + 1] * 0.125f;
                float inter = fminf(aw, gw) * fminf(ah, gh);
                float uni   = aw * ah + gw * gh - inter;
                float r     = inter / uni;
                if (r > bestr) { bestr = r; best = a; }   // first-wins ties, like argmax
            }
            int b = bidx[n];
            int key = ((b * 3 + best) * 128 + gj) * 128 + gi;
            skey[n]  = key;
            mykey[k] = key;
            atomicAdd(&scnt[b], 1);
        }
        __syncthreads();

        // ---- maxseg = max boxes in any batch (bound on duplicate-pair distance) ----
        if (t < 64) {
            int v = scnt[t];
            #pragma unroll
            for (int off = 32; off > 0; off >>= 1) v = max(v, __shfl_down(v, off, 64));
            if (t == 0) scnt[0] = v;
        }
        __syncthreads();
        const int maxseg = scnt[0];

        // ---- phase 2: dedup, last-write-wins. Fixed trip count, branch-free,
        //      independent LDS reads (throughput ~6cyc, not 120cyc latency). ----
        bool win[5];
        #pragma unroll
        for (int k = 0; k < 5; k++) win[k] = true;
        for (int d = 1; d <= maxseg; d++) {
            #pragma unroll
            for (int k = 0; k < 5; k++) {
                int m2 = t + k * 256 + d;
                int mc = m2 < NBOX ? m2 : NBOX - 1;       // clamp (guard result below)
                int other = skey[mc];
                if (m2 < NBOX && other == mykey[k]) win[k] = false;
            }
        }

        // ---- phase 3: winners recompute targets + gather pred + accumulate ----
        #pragma unroll
        for (int k = 0; k < 5; k++) {
            if (!win[k]) continue;
            int n = t + k * 256;
            float gx = gbox[n * 4 + 0] * 0.125f;
            float gy = gbox[n * 4 + 1] * 0.125f;
            float gw = gbox[n * 4 + 2] * 0.125f;
            float gh = gbox[n * 4 + 3] * 0.125f;
            int gi = (int)gx, gj = (int)gy;
            int best = 0; float bestr = -1.f, baw = 1.f, bah = 1.f;
            #pragma unroll
            for (int a = 0; a < 3; a++) {
                float aw = anch[a * 2 + 0] * 0.125f;
                float ah = anch[a * 2 + 1] * 0.125f;
                float inter = fminf(aw, gw) * fminf(ah, gh);
                float uni   = aw * ah + gw * gh - inter;
                float r     = inter / uni;
                if (r > bestr) { bestr = r; best = a; baw = aw; bah = ah; }
            }
            float tx = gx - (float)gi;
            float ty = gy - (float)gj;
            float tw = __logf(gw / baw);
            float th = __logf(gh / bah);
            int b = bidx[n];
            long base = ((((long)b * GVAL + gj) * GVAL) + gi) * 15 + best * 5;
            float conf = yp[base + 0];
            float px = 1.f / (1.f + __expf(-yp[base + 1]));
            float py = 1.f / (1.f + __expf(-yp[base + 2]));
            float pw = yp[base + 3];
            float ph = yp[base + 4];
            float dx = px - tx, dy = py - ty, dw = pw - tw, dh = ph - th;
            float lp = __logf(1.f + __expf(-fabsf(conf)));
            float sp_pos = fmaxf( conf, 0.f) + lp;   // softplus(conf)
            float sp_neg = fmaxf(-conf, 0.f) + lp;   // softplus(-conf)
            acc += 5.f * (dx * dx + dy * dy + dw * dw + dh * dh)
                 + sp_neg - 0.5f * sp_pos;           // obj minus over-counted noobj
        }
    } else {
        // ---- noobj sweep: 0.5 * sum softplus(conf at channels {0,5,10} mod 15) ----
        const float4* yp4 = (const float4*)yp;
        float4* sm4 = (float4*)sm;
        float lacc = 0.f;
        for (int tile = (int)blockIdx.x - 1; tile < NTILES; tile += (int)gridDim.x - 1) {
            const float4* src = yp4 + (long)tile * TILE_V4;
            sm4[t]       = src[t];
            sm4[t + 256] = src[t + 256];
            sm4[t + 512] = src[t + 512];
            if (t < 192) sm4[t + 768] = src[t + 768];
            __syncthreads();
            // thread t owns group t: confs at words t*15 + {0,5,10}
            // (stride 15 coprime to 32 banks; lanes t,t+32 are 2-way = free)
            int w = t * 15;
            lacc += softplus_f(sm[w]) + softplus_f(sm[w + 5]) + softplus_f(sm[w + 10]);
            __syncthreads();   // before LDS reuse next tile
        }
        acc = 0.5f * lacc;
    }

    // ---- block reduction: wave shuffle -> LDS -> one atomic per block ----
    #pragma unroll
    for (int off = 32; off > 0; off >>= 1) acc += __shfl_down(acc, off, 64);
    int lane = t & 63, wid = t >> 6;
    if (lane == 0) swave[wid] = acc;
    __syncthreads();
    if (t == 0) {
        float s = swave[0] + swave[1] + swave[2] + swave[3];
        atomicAdd(out, s);
    }
}

extern "C" void kernel_launch(void* const* d_in, const int* in_sizes, int n_in,
                              void* d_out, int out_size, void* d_ws, size_t ws_size,
                              hipStream_t stream) {
    const float* yp   = (const float*)d_in[0];   // y_pred (B,G,G,15) fp32
    const float* gbox = (const float*)d_in[1];   // ground_bboxes (N,4) fp32
    const float* anch = (const float*)d_in[2];   // anchors (3,2) fp32
    const int*   bidx = (const int*)d_in[3];     // batch_idx (N,) int32

    float* out = (float*)d_out;
    hipMemsetAsync(out, 0, sizeof(float), stream);  // d_out is re-poisoned each replay

    // 1 box block + 2048 sweep blocks (exactly 2 tiles per sweep block)
    yolo_loss_kernel<<<dim3(2049), dim3(256), 0, stream>>>(yp, gbox, anch, bidx, out);
}

// Round 4
// 112.617 us; speedup vs baseline: 1.1092x; 1.0367x over previous
//
#include <hip/hip_runtime.h>
#include <math.h>

// Problem constants: IMG_SIZE=1024, B=64, G=128, A=3, N=1280, stride=8
#define NBOX     1280
#define BVAL     64
#define GVAL     128
#define NFLOAT   (BVAL * GVAL * GVAL * 15)   // 15,728,640 floats = 62.9 MB
#define NVEC     (NFLOAT / 4)                // 3,932,160 float4
#define TILE_V4  960                         // float4 per tile = 3840 floats = 256 groups
#define TILE_F   3840
#define NTILES   (NVEC / TILE_V4)            // 4096 exactly
#define NBLK     2049                        // 1 box block + 2048 sweep blocks

__device__ __forceinline__ float softplus_f(float z) {
    return fmaxf(z, 0.f) + __logf(1.f + __expf(-fabsf(z)));
}

// blockIdx 0       : target build + dedup (fixed-trip, branch-free) + gather-adjust
// blockIdx 1..2048 : LDS-staged noobj sweep, 2 tiles each (4096 tiles total)
// Each block stores its partial sum to part[blockIdx] — NO same-address atomics
// (R3 post-mortem: 2049 same-line atomicAdds serialized at ~20 ns each = the
//  entire 42 µs dispatch; WRITE_SIZE was exactly 2049*32 B of line bounces).
__global__ void __launch_bounds__(256) yolo_loss_kernel(
    const float* __restrict__ yp,
    const float* __restrict__ gbox,
    const float* __restrict__ anch,
    const int*   __restrict__ bidx,
    float*       __restrict__ part)
{
    __shared__ float sm[TILE_F];   // 15360 B; box block aliases skey/scnt over it
    __shared__ float swave[4];

    const int t = threadIdx.x;
    float acc = 0.f;

    if (blockIdx.x == 0) {
        int* skey = (int*)sm;          // [0,1280) keys
        int* scnt = skey + NBOX;       // [0,64) per-batch counts; scnt[0] reused for maxseg

        if (t < BVAL) scnt[t] = 0;
        __syncthreads();

        // ---- phase 1: per-box key (kept in regs too) + batch histogram ----
        int mykey[5];
        #pragma unroll
        for (int k = 0; k < 5; k++) {
            int n = t + k * 256;                     // 5*256 == NBOX exactly
            float gx = gbox[n * 4 + 0] * 0.125f;
            float gy = gbox[n * 4 + 1] * 0.125f;
            float gw = gbox[n * 4 + 2] * 0.125f;
            float gh = gbox[n * 4 + 3] * 0.125f;
            int gi = (int)gx, gj = (int)gy;
            int best = 0; float bestr = -1.f;
            #pragma unroll
            for (int a = 0; a < 3; a++) {
                float aw = anch[a * 2 + 0] * 0.125f;
                float ah = anch[a * 2 + 1] * 0.125f;
                float inter = fminf(aw, gw) * fminf(ah, gh);
                float uni   = aw * ah + gw * gh - inter;
                float r     = inter / uni;
                if (r > bestr) { bestr = r; best = a; }   // first-wins ties, like argmax
            }
            int b = bidx[n];
            int key = ((b * 3 + best) * 128 + gj) * 128 + gi;
            skey[n]  = key;
            mykey[k] = key;
            atomicAdd(&scnt[b], 1);                  // LDS atomic — cheap
        }
        __syncthreads();

        // ---- maxseg = max boxes in any batch (bound on duplicate-pair distance) ----
        if (t < 64) {
            int v = scnt[t];
            #pragma unroll
            for (int off = 32; off > 0; off >>= 1) v = max(v, __shfl_down(v, off, 64));
            if (t == 0) scnt[0] = v;
        }
        __syncthreads();
        const int maxseg = scnt[0];

        // ---- phase 2: dedup, last-write-wins; fixed trip count, branch-free ----
        bool win[5];
        #pragma unroll
        for (int k = 0; k < 5; k++) win[k] = true;
        for (int d = 1; d <= maxseg; d++) {
            #pragma unroll
            for (int k = 0; k < 5; k++) {
                int m2 = t + k * 256 + d;
                int mc = m2 < NBOX ? m2 : NBOX - 1;       // clamp (guard result below)
                int other = skey[mc];
                if (m2 < NBOX && other == mykey[k]) win[k] = false;
            }
        }

        // ---- phase 3: winners recompute targets + gather pred + accumulate ----
        #pragma unroll
        for (int k = 0; k < 5; k++) {
            if (!win[k]) continue;
            int n = t + k * 256;
            float gx = gbox[n * 4 + 0] * 0.125f;
            float gy = gbox[n * 4 + 1] * 0.125f;
            float gw = gbox[n * 4 + 2] * 0.125f;
            float gh = gbox[n * 4 + 3] * 0.125f;
            int gi = (int)gx, gj = (int)gy;
            int best = 0; float bestr = -1.f, baw = 1.f, bah = 1.f;
            #pragma unroll
            for (int a = 0; a < 3; a++) {
                float aw = anch[a * 2 + 0] * 0.125f;
                float ah = anch[a * 2 + 1] * 0.125f;
                float inter = fminf(aw, gw) * fminf(ah, gh);
                float uni   = aw * ah + gw * gh - inter;
                float r     = inter / uni;
                if (r > bestr) { bestr = r; best = a; baw = aw; bah = ah; }
            }
            float tx = gx - (float)gi;
            float ty = gy - (float)gj;
            float tw = __logf(gw / baw);
            float th = __logf(gh / bah);
            int b = bidx[n];
            long base = ((((long)b * GVAL + gj) * GVAL) + gi) * 15 + best * 5;
            float conf = yp[base + 0];
            float px = 1.f / (1.f + __expf(-yp[base + 1]));
            float py = 1.f / (1.f + __expf(-yp[base + 2]));
            float pw = yp[base + 3];
            float ph = yp[base + 4];
            float dx = px - tx, dy = py - ty, dw = pw - tw, dh = ph - th;
            float lp = __logf(1.f + __expf(-fabsf(conf)));
            float sp_pos = fmaxf( conf, 0.f) + lp;   // softplus(conf)
            float sp_neg = fmaxf(-conf, 0.f) + lp;   // softplus(-conf)
            acc += 5.f * (dx * dx + dy * dy + dw * dw + dh * dh)
                 + sp_neg - 0.5f * sp_pos;           // obj minus over-counted noobj
        }
    } else {
        // ---- noobj sweep: 0.5 * sum softplus(conf at channels {0,5,10} mod 15) ----
        const float4* yp4 = (const float4*)yp;
        float4* sm4 = (float4*)sm;
        float lacc = 0.f;
        for (int tile = (int)blockIdx.x - 1; tile < NTILES; tile += (int)gridDim.x - 1) {
            const float4* src = yp4 + (long)tile * TILE_V4;
            sm4[t]       = src[t];
            sm4[t + 256] = src[t + 256];
            sm4[t + 512] = src[t + 512];
            if (t < 192) sm4[t + 768] = src[t + 768];
            __syncthreads();
            // thread t owns group t: confs at words t*15 + {0,5,10}
            // (stride 15 coprime to 32 banks; lanes t,t+32 are 2-way = free)
            int w = t * 15;
            lacc += softplus_f(sm[w]) + softplus_f(sm[w + 5]) + softplus_f(sm[w + 10]);
            __syncthreads();   // before LDS reuse next tile
        }
        acc = 0.5f * lacc;
    }

    // ---- block reduction: wave shuffle -> LDS -> ONE PLAIN STORE per block ----
    #pragma unroll
    for (int off = 32; off > 0; off >>= 1) acc += __shfl_down(acc, off, 64);
    int lane = t & 63, wid = t >> 6;
    if (lane == 0) swave[wid] = acc;
    __syncthreads();
    if (t == 0) part[blockIdx.x] = swave[0] + swave[1] + swave[2] + swave[3];
}

// Single-block final reduce of the 2049 partials; writes out[0] directly
// (no memset dispatch needed — plain store overwrites the poison).
__global__ void __launch_bounds__(256) final_reduce_kernel(
    const float* __restrict__ part, float* __restrict__ out)
{
    __shared__ float swave[4];
    const int t = threadIdx.x;
    float acc = 0.f;
    for (int i = t; i < NBLK; i += 256) acc += part[i];
    #pragma unroll
    for (int off = 32; off > 0; off >>= 1) acc += __shfl_down(acc, off, 64);
    int lane = t & 63, wid = t >> 6;
    if (lane == 0) swave[wid] = acc;
    __syncthreads();
    if (t == 0) out[0] = swave[0] + swave[1] + swave[2] + swave[3];
}

extern "C" void kernel_launch(void* const* d_in, const int* in_sizes, int n_in,
                              void* d_out, int out_size, void* d_ws, size_t ws_size,
                              hipStream_t stream) {
    const float* yp   = (const float*)d_in[0];   // y_pred (B,G,G,15) fp32
    const float* gbox = (const float*)d_in[1];   // ground_bboxes (N,4) fp32
    const float* anch = (const float*)d_in[2];   // anchors (3,2) fp32
    const int*   bidx = (const int*)d_in[3];     // batch_idx (N,) int32
    float* part = (float*)d_ws;                  // NBLK partials (8196 B)
    float* out  = (float*)d_out;

    yolo_loss_kernel<<<dim3(NBLK), dim3(256), 0, stream>>>(yp, gbox, anch, bidx, part);
    final_reduce_kernel<<<dim3(1), dim3(256), 0, stream>>>(part, out);
}

// Round 5
// 111.625 us; speedup vs baseline: 1.1191x; 1.0089x over previous
//
#include <hip/hip_runtime.h>
#include <math.h>

// Problem constants: IMG_SIZE=1024, B=64, G=128, A=3, N=1280, stride=8
#define NBOX     1280
#define BVAL     64
#define GVAL     128
#define NFLOAT   (BVAL * GVAL * GVAL * 15)   // 15,728,640 floats = 62.9 MB
#define NVEC     (NFLOAT / 4)                // 3,932,160 float4
#define SPAN_V4  1920                        // float4 per sweep block = 7680 floats = 512 groups
#define SPAN_F   7680
#define NSWEEP   (NVEC / SPAN_V4)            // 2048 exactly
#define NBLK     (NSWEEP + 1)                // + 1 box block

__device__ __forceinline__ float softplus_f(float z) {
    return fmaxf(z, 0.f) + __logf(1.f + __expf(-fabsf(z)));
}

// blockIdx 0       : target build + dedup (fixed-trip, branch-free) + gather-adjust
// blockIdx 1..2048 : noobj sweep, one contiguous 30 KB span per block,
//                    single LDS stage + ONE barrier (was 2 tiles × 2 barriers).
// Partials via plain per-block stores — NO same-address atomics (R3: 2049
// same-line atomicAdds serialized at ~20 ns each = 42 µs of dead time).
__global__ void __launch_bounds__(256) yolo_loss_kernel(
    const float* __restrict__ yp,
    const float* __restrict__ gbox,
    const float* __restrict__ anch,
    const int*   __restrict__ bidx,
    float*       __restrict__ part)
{
    __shared__ float sm[SPAN_F];   // 30720 B -> 5 blocks/CU, 20 waves: enough TLP
    __shared__ float swave[4];

    const int t = threadIdx.x;
    float acc = 0.f;

    if (blockIdx.x == 0) {
        int* skey = (int*)sm;          // [0,1280) keys
        int* scnt = skey + NBOX;       // 64 per-batch counts; scnt[0] reused for maxseg

        if (t < BVAL) scnt[t] = 0;
        __syncthreads();

        // ---- phase 1: per-box key (kept in regs too) + batch histogram ----
        int mykey[5];
        #pragma unroll
        for (int k = 0; k < 5; k++) {
            int n = t + k * 256;                     // 5*256 == NBOX exactly
            float gx = gbox[n * 4 + 0] * 0.125f;
            float gy = gbox[n * 4 + 1] * 0.125f;
            float gw = gbox[n * 4 + 2] * 0.125f;
            float gh = gbox[n * 4 + 3] * 0.125f;
            int gi = (int)gx, gj = (int)gy;
            int best = 0; float bestr = -1.f;
            #pragma unroll
            for (int a = 0; a < 3; a++) {
                float aw = anch[a * 2 + 0] * 0.125f;
                float ah = anch[a * 2 + 1] * 0.125f;
                float inter = fminf(aw, gw) * fminf(ah, gh);
                float uni   = aw * ah + gw * gh - inter;
                float r     = inter / uni;
                if (r > bestr) { bestr = r; best = a; }   // first-wins ties, like argmax
            }
            int b = bidx[n];
            int key = ((b * 3 + best) * 128 + gj) * 128 + gi;
            skey[n]  = key;
            mykey[k] = key;
            atomicAdd(&scnt[b], 1);                  // LDS atomic — cheap
        }
        __syncthreads();

        // ---- maxseg = max boxes in any batch (bound on duplicate-pair distance) ----
        if (t < 64) {
            int v = scnt[t];
            #pragma unroll
            for (int off = 32; off > 0; off >>= 1) v = max(v, __shfl_down(v, off, 64));
            if (t == 0) scnt[0] = v;
        }
        __syncthreads();
        const int maxseg = scnt[0];

        // ---- phase 2: dedup, last-write-wins; fixed trip count, branch-free ----
        bool win[5];
        #pragma unroll
        for (int k = 0; k < 5; k++) win[k] = true;
        for (int d = 1; d <= maxseg; d++) {
            #pragma unroll
            for (int k = 0; k < 5; k++) {
                int m2 = t + k * 256 + d;
                int mc = m2 < NBOX ? m2 : NBOX - 1;       // clamp (guard result below)
                int other = skey[mc];
                if (m2 < NBOX && other == mykey[k]) win[k] = false;
            }
        }

        // ---- phase 3: winners recompute targets + gather pred + accumulate ----
        #pragma unroll
        for (int k = 0; k < 5; k++) {
            if (!win[k]) continue;
            int n = t + k * 256;
            float gx = gbox[n * 4 + 0] * 0.125f;
            float gy = gbox[n * 4 + 1] * 0.125f;
            float gw = gbox[n * 4 + 2] * 0.125f;
            float gh = gbox[n * 4 + 3] * 0.125f;
            int gi = (int)gx, gj = (int)gy;
            int best = 0; float bestr = -1.f, baw = 1.f, bah = 1.f;
            #pragma unroll
            for (int a = 0; a < 3; a++) {
                float aw = anch[a * 2 + 0] * 0.125f;
                float ah = anch[a * 2 + 1] * 0.125f;
                float inter = fminf(aw, gw) * fminf(ah, gh);
                float uni   = aw * ah + gw * gh - inter;
                float r     = inter / uni;
                if (r > bestr) { bestr = r; best = a; baw = aw; bah = ah; }
            }
            float tx = gx - (float)gi;
            float ty = gy - (float)gj;
            float tw = __logf(gw / baw);
            float th = __logf(gh / bah);
            int b = bidx[n];
            long base = ((((long)b * GVAL + gj) * GVAL) + gi) * 15 + best * 5;
            float conf = yp[base + 0];
            float px = 1.f / (1.f + __expf(-yp[base + 1]));
            float py = 1.f / (1.f + __expf(-yp[base + 2]));
            float pw = yp[base + 3];
            float ph = yp[base + 4];
            float dx = px - tx, dy = py - ty, dw = pw - tw, dh = ph - th;
            float lp = __logf(1.f + __expf(-fabsf(conf)));
            float sp_pos = fmaxf( conf, 0.f) + lp;   // softplus(conf)
            float sp_neg = fmaxf(-conf, 0.f) + lp;   // softplus(-conf)
            acc += 5.f * (dx * dx + dy * dy + dw * dw + dh * dh)
                 + sp_neg - 0.5f * sp_pos;           // obj minus over-counted noobj
        }
    } else {
        // ---- noobj sweep: 0.5 * sum softplus(conf at channels {0,5,10} mod 15) ----
        // One 30 KB span per block, staged with 8 coalesced float4 waves,
        // ONE barrier, then 512 groups (2/thread) read from LDS.
        const float4* src = (const float4*)yp + (long)(blockIdx.x - 1) * SPAN_V4;
        float4* sm4 = (float4*)sm;
        #pragma unroll
        for (int k = 0; k < 7; k++) sm4[t + k * 256] = src[t + k * 256];
        if (t < 128) sm4[t + 1792] = src[t + 1792];   // 1920 = 7.5 * 256
        __syncthreads();
        // groups g = t and g = t + 256; confs at words 15g + {0,5,10}
        // (stride 15 coprime to 32 banks; lanes t,t+32 are 2-way = free)
        int w0 = t * 15;
        int w1 = (t + 256) * 15;
        float lacc = softplus_f(sm[w0]) + softplus_f(sm[w0 + 5]) + softplus_f(sm[w0 + 10])
                   + softplus_f(sm[w1]) + softplus_f(sm[w1 + 5]) + softplus_f(sm[w1 + 10]);
        acc = 0.5f * lacc;
    }

    // ---- block reduction: wave shuffle -> LDS -> ONE PLAIN STORE per block ----
    #pragma unroll
    for (int off = 32; off > 0; off >>= 1) acc += __shfl_down(acc, off, 64);
    int lane = t & 63, wid = t >> 6;
    if (lane == 0) swave[wid] = acc;
    __syncthreads();
    if (t == 0) part[blockIdx.x] = swave[0] + swave[1] + swave[2] + swave[3];
}

// Single-block final reduce of the 2049 partials; writes out[0] directly
// (plain store overwrites the 0xAA poison — no memset dispatch needed).
__global__ void __launch_bounds__(256) final_reduce_kernel(
    const float* __restrict__ part, float* __restrict__ out)
{
    __shared__ float swave[4];
    const int t = threadIdx.x;
    float acc = 0.f;
    for (int i = t; i < NBLK; i += 256) acc += part[i];
    #pragma unroll
    for (int off = 32; off > 0; off >>= 1) acc += __shfl_down(acc, off, 64);
    int lane = t & 63, wid = t >> 6;
    if (lane == 0) swave[wid] = acc;
    __syncthreads();
    if (t == 0) out[0] = swave[0] + swave[1] + swave[2] + swave[3];
}

extern "C" void kernel_launch(void* const* d_in, const int* in_sizes, int n_in,
                              void* d_out, int out_size, void* d_ws, size_t ws_size,
                              hipStream_t stream) {
    const float* yp   = (const float*)d_in[0];   // y_pred (B,G,G,15) fp32
    const float* gbox = (const float*)d_in[1];   // ground_bboxes (N,4) fp32
    const float* anch = (const float*)d_in[2];   // anchors (3,2) fp32
    const int*   bidx = (const int*)d_in[3];     // batch_idx (N,) int32
    float* part = (float*)d_ws;                  // NBLK partials (8196 B)
    float* out  = (float*)d_out;

    yolo_loss_kernel<<<dim3(NBLK), dim3(256), 0, stream>>>(yp, gbox, anch, bidx, part);
    final_reduce_kernel<<<dim3(1), dim3(256), 0, stream>>>(part, out);
}